// Round 4
// baseline (1473.994 us; speedup 1.0000x reference)
//
#include <hip/hip_runtime.h>
#include <hip/hip_cooperative_groups.h>
#include <cstdint>

namespace cg = cooperative_groups;

#define NN 8192
#define DD 256
#define KS 8                     // k-splits for the dense levels
#define CSRSZ ((1 << 17) + NN)   // per-list csr capacity (E + slack)

typedef unsigned short u16;
typedef __bf16 bf16_t;
typedef __bf16 bf16x8 __attribute__((ext_vector_type(8)));
typedef float f32x4 __attribute__((ext_vector_type(4)));

// native HW convert (v_cvt_pk_bf16_f32, RNE) instead of bit-twiddled RNE
__device__ __forceinline__ u16 f2bf(float f) {
    union { bf16_t h; u16 u; } c; c.h = (bf16_t)f; return c.u;
}

__device__ __forceinline__ void cvt_store8(f32x4 a, f32x4 b, u16* dst) {
    union { bf16_t h[8]; uint4 v; } pk;
    pk.h[0] = (bf16_t)a[0]; pk.h[1] = (bf16_t)a[1];
    pk.h[2] = (bf16_t)a[2]; pk.h[3] = (bf16_t)a[3];
    pk.h[4] = (bf16_t)b[0]; pk.h[5] = (bf16_t)b[1];
    pk.h[6] = (bf16_t)b[2]; pk.h[7] = (bf16_t)b[3];
    *(uint4*)dst = pk.v;
}

// ---------------------------------------------------------------------------
// GEMM: C[M x 256] = A[M x K] * B[K x 256], B given transposed (BT[n][k], bf16).
// A fp32 (AF32=1, converted in-kernel via v_cvt_pk) or bf16 (AF32=0).
// Tile 64(m) x 256(n) x 32(k-step); 4 waves; wave w owns n in [64w, 64w+64).
// 2-phase software pipeline: stage(t+1) issued BEFORE compute(t), double-
// buffered LDS, one barrier per k-step.  Split-K: block z writes slab
// C + z*NN*DD (no atomics); reduction fused into the norm kernels.
// ROWSUM: wave 0 accumulates rowsum(A) via ones-column B fragment.
// KS=8 -> 1024 blocks (~3/CU, LDS 40KiB allows 4) for latency hiding.
// ---------------------------------------------------------------------------
template<bool AF32, bool ROWSUM>
__global__ __launch_bounds__(256, 2)
void gemm_k(const void* __restrict__ Ap, long ldA,
            const u16* __restrict__ BT, long ldBT,
            float* __restrict__ C, float* __restrict__ rs, int kPer)
{
    __shared__ __align__(16) u16 As[2][64 * 32];
    __shared__ __align__(16) u16 Bs[2][256 * 32];

    const int tid  = threadIdx.x;
    const int lane = tid & 63;
    const int wave = tid >> 6;       // 0..3
    const int r    = lane & 15;
    const int q    = lane >> 4;
    const long m0  = (long)blockIdx.x * 64;
    const long k0  = (long)blockIdx.z * kPer;
    float* __restrict__ Cs = C + (long)blockIdx.z * ((long)NN * DD);

    f32x4 acc[4][4] = {};
    f32x4 racc[4]   = {};
    bf16x8 ones;
    if constexpr (ROWSUM) {
        union { bf16x8 v; u16 u[8]; } cv;
        u16 pat = (r == 0) ? (u16)0x3F80 : (u16)0;   // 1.0 in n-col 0
        #pragma unroll
        for (int j = 0; j < 8; ++j) cv.u[j] = pat;
        ones = cv.v;
    }

    // B staging: wave loads groups 4w..4w+3 (rows wave*64 + g2*16 + r)
    const u16* bBase = BT + (long)(wave * 64 + r) * ldBT + k0 + q * 8;
    // A staging (AF32): thread t handles row t>>2, k-octet t&3 (8 fp32 -> 8 bf16)
    const int arow = tid >> 2;
    const int kq8  = tid & 3;
    const float* aBaseF = AF32 ? ((const float*)Ap + (m0 + arow) * ldA + k0 + kq8 * 8) : nullptr;
    u16* const aDst0 = &As[0][(arow >> 4) * 512 + (kq8 * 16 + (arow & 15)) * 8];
    u16* const aDst1 = &As[1][(arow >> 4) * 512 + (kq8 * 16 + (arow & 15)) * 8];
    // A staging (bf16): wave loads group `wave` via global_load_lds
    const u16* aBaseH = AF32 ? nullptr
                             : ((const u16*)Ap + (m0 + wave * 16 + r) * ldA + k0 + q * 8);
    const int nsteps = kPer >> 5;

#define STAGE_B(t, buf) do {                                                      \
    const long koff_ = (long)(t) << 5;                                            \
    _Pragma("unroll")                                                             \
    for (int g2_ = 0; g2_ < 4; ++g2_)                                             \
        __builtin_amdgcn_global_load_lds(                                         \
            (const __attribute__((address_space(1))) void*)(bBase + (long)g2_ * 16 * ldBT + koff_), \
            (__attribute__((address_space(3))) void*)(&Bs[buf][(wave * 4 + g2_) * 512 + lane * 8]), \
            16, 0, 0);                                                            \
  } while (0)

#define STAGE_AH(t, buf)                                                          \
    __builtin_amdgcn_global_load_lds(                                             \
        (const __attribute__((address_space(1))) void*)(aBaseH + ((long)(t) << 5)), \
        (__attribute__((address_space(3))) void*)(&As[buf][wave * 512 + lane * 8]), \
        16, 0, 0)

    // ---- prologue: stage tile 0 into buffer 0
    STAGE_B(0, 0);
    if constexpr (AF32) {
        f32x4 p0 = __builtin_nontemporal_load((const f32x4*)aBaseF);
        f32x4 p1 = __builtin_nontemporal_load((const f32x4*)(aBaseF + 4));
        cvt_store8(p0, p1, aDst0);
    } else {
        STAGE_AH(0, 0);
    }
    __syncthreads();

    for (int t = 0; t < nsteps; ++t) {
        const int cur = t & 1, nxt = cur ^ 1;
        const bool more = (t + 1 < nsteps);
        f32x4 na0, na1;
        if (more) {
            STAGE_B(t + 1, nxt);                    // async, lands during compute
            if constexpr (AF32) {
                const float* ap = aBaseF + ((long)(t + 1) << 5);
                na0 = __builtin_nontemporal_load((const f32x4*)ap);
                na1 = __builtin_nontemporal_load((const f32x4*)(ap + 4));
            } else {
                STAGE_AH(t + 1, nxt);
            }
        }
        bf16x8 af[4], bfr[4];
        #pragma unroll
        for (int i = 0; i < 4; ++i) {
            af[i]  = *(const bf16x8*)(&As[cur][i * 512 + lane * 8]);
            bfr[i] = *(const bf16x8*)(&Bs[cur][(wave * 4 + i) * 512 + lane * 8]);
        }
        #pragma unroll
        for (int i = 0; i < 4; ++i)
            #pragma unroll
            for (int j = 0; j < 4; ++j)
                acc[i][j] = __builtin_amdgcn_mfma_f32_16x16x32_bf16(af[i], bfr[j], acc[i][j], 0, 0, 0);
        if constexpr (ROWSUM) {
            if (wave == 0) {
                #pragma unroll
                for (int i = 0; i < 4; ++i)
                    racc[i] = __builtin_amdgcn_mfma_f32_16x16x32_bf16(af[i], ones, racc[i], 0, 0, 0);
            }
        }
        if constexpr (AF32) {
            if (more) cvt_store8(na0, na1, (nxt ? aDst1 : aDst0));  // waits its loads here
        }
        __syncthreads();
    }
#undef STAGE_B
#undef STAGE_AH

    // epilogue: C/D layout col = lane&15, row = (lane>>4)*4 + reg
    #pragma unroll
    for (int i = 0; i < 4; ++i) {
        const long rowb = m0 + i * 16 + q * 4;
        #pragma unroll
        for (int j = 0; j < 4; ++j) {
            const long col = wave * 64 + j * 16 + r;
            #pragma unroll
            for (int rr2 = 0; rr2 < 4; ++rr2)
                Cs[(rowb + rr2) * DD + col] = acc[i][j][rr2];
        }
        if constexpr (ROWSUM) {
            if (wave == 0 && r == 0) {
                #pragma unroll
                for (int rr2 = 0; rr2 < 4; ++rr2)
                    rs[(long)blockIdx.z * NN + rowb + rr2] = racc[i][rr2];
            }
        }
    }
}

// ---------------------------------------------------------------------------
// fused transpose-convert: blocks 0..511 -> emb0 [8192][256] -> embT [256][8192]
// blocks 512..543 -> Wsame/Wtop [256][256] -> WT slabs. 64x64 tiles.
// ---------------------------------------------------------------------------
__global__ __launch_bounds__(256)
void trans_k(const float* __restrict__ emb0,
             const float* __restrict__ w0, const float* __restrict__ w1,
             u16* __restrict__ embT, u16* __restrict__ WT)
{
    __shared__ u16 t[64][72];
    const int b = blockIdx.x;
    const float* src; u16* dst; long R, C, r0, c0;
    if (b < 512) {
        src = emb0; dst = embT; R = NN; C = DD;
        r0 = (long)(b & 127) * 64; c0 = (long)(b >> 7) * 64;
    } else {
        const int w = b - 512;             // 0..31
        const int which = w >> 4, tt = w & 15;
        src = which ? w1 : w0; dst = WT + (size_t)which * DD * DD;
        R = DD; C = DD;
        r0 = (long)(tt & 3) * 64; c0 = (long)(tt >> 2) * 64;
    }
    const int tid = threadIdx.x;
    const int rr = tid >> 2;
    const int cc = (tid & 3) << 4;
    const float* sp = src + (r0 + rr) * C + c0 + cc;
    #pragma unroll
    for (int j = 0; j < 16; ++j) t[cc + j][rr] = f2bf(sp[j]);
    __syncthreads();
    u16* dp = dst + (c0 + rr) * R + r0 + cc;
    #pragma unroll
    for (int j = 0; j < 16; ++j) dp[j] = t[rr][cc + j];
}

// ---------------------------------------------------------------------------
// norm0: v = (resid + sum_s Cacc[s]) * 1/(sum_s rs[s]+1); write outF fp32
// [N][256] AND outT bf16 [256][N] (transposed). 64x64 tiles.
// ---------------------------------------------------------------------------
__global__ __launch_bounds__(256)
void norm0_k(const float* __restrict__ Cacc, const float* __restrict__ rs,
             const float* __restrict__ resid,
             float* __restrict__ outF, u16* __restrict__ outT)
{
    __shared__ u16 t[64][72];
    const int tid = threadIdx.x;
    const int rr = tid >> 2;
    const int cc = (tid & 3) << 4;
    const long i0 = (long)blockIdx.x * 64;
    const int  n0 = blockIdx.y * 64;
    const long i  = i0 + rr;
    float rsum = 0.0f;
    #pragma unroll
    for (int s2 = 0; s2 < KS; ++s2) rsum += rs[s2 * NN + i];
    const float scale = 1.0f / (rsum + 1.0f);
    const float* c0p = Cacc + i * DD + n0 + cc;
    const float* rp  = resid + i * DD + n0 + cc;
    float* fp = outF + i * DD + n0 + cc;
    const long slab = (long)NN * DD;
    #pragma unroll
    for (int j = 0; j < 16; ++j) {
        float v = rp[j];
        #pragma unroll
        for (int s2 = 0; s2 < KS; ++s2) v += c0p[j + s2 * slab];
        v *= scale;
        fp[j] = v;
        t[cc + j][rr] = f2bf(v);
    }
    __syncthreads();
    u16* op = outT + (long)(n0 + rr) * NN + i0 + cc;
    #pragma unroll
    for (int j = 0; j < 16; ++j) op[j] = t[rr][cc + j];
}

// ---------------------------------------------------------------------------
// norm1: v = (resid + sum_s Cacc[s]) * 1/(sum_s rs[s]+1); write bf16 row-major
// [N][256]. grid 2048 x 256thr, 4 elems/thread.
// ---------------------------------------------------------------------------
__global__ __launch_bounds__(256)
void norm1_k(const float* __restrict__ Cacc, const float* __restrict__ rs,
             const float* __restrict__ resid, u16* __restrict__ outR)
{
    const long g = ((long)blockIdx.x * 256 + threadIdx.x) * 4;
    const long row = g >> 8;
    float rsum = 0.0f;
    #pragma unroll
    for (int s2 = 0; s2 < KS; ++s2) rsum += rs[s2 * NN + row];
    const float scale = 1.0f / (rsum + 1.0f);
    const long slab = (long)NN * DD;
    const float4 rv = *(const float4*)(resid + g);
    float vx = rv.x, vy = rv.y, vz = rv.z, vw = rv.w;
    #pragma unroll
    for (int s2 = 0; s2 < KS; ++s2) {
        const float4 c = *(const float4*)(Cacc + g + s2 * slab);
        vx += c.x; vy += c.y; vz += c.z; vw += c.w;
    }
    u16* op = outR + g;
    op[0] = f2bf(vx * scale);
    op[1] = f2bf(vy * scale);
    op[2] = f2bf(vz * scale);
    op[3] = f2bf(vw * scale);
}

// ---------------------------------------------------------------------------
// Cooperative fused CSR build for BOTH edge lists:
// P0 zero counts -> P1 histogram -> P2 per-256-chunk scan -> P3 chunk-sum scan
// -> P4 add bases, write offs/cursor -> P5 scatter fill. One dispatch.
// Grid 1024x256 (4 blocks/CU, co-resident; tiny LDS/VGPR).
// ---------------------------------------------------------------------------
__global__ __launch_bounds__(256)
void csr_k(const int* __restrict__ eiS, const int* __restrict__ eiU, int E,
           int* __restrict__ counts, int* __restrict__ offs,
           int* __restrict__ cursor, float* __restrict__ dinv,
           int* __restrict__ csr, int* __restrict__ csums)
{
    cg::grid_group grid = cg::this_grid();
    const int tid = threadIdx.x;
    const int gsz = gridDim.x * 256;
    const int g   = blockIdx.x * 256 + tid;

    // P0: zero both count arrays
    for (int i = g; i < 2 * NN; i += gsz) counts[i] = 0;
    grid.sync();

    // P1: histogram (dst halves of both lists)
    for (int i = g; i < 2 * E; i += gsz) {
        const int p = (i >= E);
        const int e = i - p * E;
        const int* d = (p ? eiU : eiS) + E;
        atomicAdd(counts + p * NN + d[e], 1);
    }
    grid.sync();

    // P2: 64 chunks of 256; block b scans chunk b (exclusive, chunk-local)
    __shared__ int wsum[4];
    if (blockIdx.x < (2 * NN) / 256) {
        const int chunk = blockIdx.x;            // 0..63
        const int p   = chunk >> 5;              // list
        const int idx = chunk * 256 + tid;       // combined counts index
        const int li  = idx - p * NN;            // index within list
        const int c = counts[idx];
        dinv[idx] = 1.0f / sqrtf((float)c + 1.0f);
        const int lane = tid & 63, wid = tid >> 6;
        int x = c;
        #pragma unroll
        for (int d2 = 1; d2 < 64; d2 <<= 1) {
            int y = __shfl_up(x, d2, 64);
            if (lane >= d2) x += y;
        }
        if (lane == 63) wsum[wid] = x;
        __syncthreads();
        int base = 0;
        #pragma unroll
        for (int wv = 0; wv < 3; ++wv) if (wv < wid) base += wsum[wv];
        offs[p * (NN + 1) + li] = base + x - c;  // chunk-local exclusive
        if (tid == 255) csums[chunk] = base + x; // chunk total
    }
    grid.sync();

    // P3: segmented exclusive scan of the 64 chunk sums (lanes 0..31 list 0,
    // 32..63 list 1) by wave 0 of block 0
    if (blockIdx.x == 0 && tid < 64) {
        const int lane = tid;
        const int v = csums[lane];
        int x = v;
        #pragma unroll
        for (int d2 = 1; d2 < 32; d2 <<= 1) {
            int y = __shfl_up(x, d2, 64);
            if ((lane & 31) >= d2) x += y;
        }
        csums[lane] = x - v;                     // segment-exclusive
        if (lane == 31) offs[NN] = x;            // total list 0
        if (lane == 63) offs[(NN + 1) + NN] = x; // total list 1
    }
    grid.sync();

    // P4: add chunk bases; init cursor
    for (int i = g; i < 2 * NN; i += gsz) {
        const int p  = i >> 13;
        const int li = i & (NN - 1);
        const int v = offs[p * (NN + 1) + li] + csums[i >> 8];
        offs[p * (NN + 1) + li] = v;
        cursor[i] = v;
    }
    grid.sync();

    // P5: scatter fill
    for (int i = g; i < 2 * E; i += gsz) {
        const int p = (i >= E);
        const int e = i - p * E;
        const int* srcl = p ? eiU : eiS;
        const int pos = atomicAdd(cursor + p * NN + srcl[E + e], 1);
        csr[p * CSRSZ + pos] = srcl[e];
    }
}

// ---------------------------------------------------------------------------
// gather: out[i] = b + dinv[i]^2*h[i] + sum_{e:dst=i} dinv[i]*dinv[src]*h[src]
// one wave per node, lane owns 4 features. csr indices + weights prefetched
// lane-parallel, then 4 independent row loads per unrolled step.
// ---------------------------------------------------------------------------
__global__ __launch_bounds__(256)
void gather_k(const float* __restrict__ h,
              const int* __restrict__ offs,
              const int* __restrict__ csr,
              const float* __restrict__ dinv,
              const float* __restrict__ bias,
              u16* __restrict__ outBF,
              float* __restrict__ outF)
{
    const int node = blockIdx.x * 4 + (threadIdx.x >> 6);
    const int lane = threadIdx.x & 63;
    const float di = dinv[node];
    const float4 hs = ((const float4*)(h + (long)node * DD))[lane];
    const float s0 = di * di;
    float4 acc;
    acc.x = hs.x * s0; acc.y = hs.y * s0; acc.z = hs.z * s0; acc.w = hs.w * s0;

    const int b0 = offs[node], b1 = offs[node + 1];
    for (int base = b0; base < b1; base += 64) {
        const int nb = (b1 - base < 64) ? (b1 - base) : 64;
        int   sidx = node;
        float wv   = 0.0f;
        if (lane < nb) {                       // prefetch indices + weights
            sidx = csr[base + lane];
            wv   = di * dinv[sidx];
        }
        int e = 0;
        for (; e + 4 <= nb; e += 4) {
            const int   i0 = __shfl(sidx, e),     i1 = __shfl(sidx, e + 1);
            const int   i2 = __shfl(sidx, e + 2), i3 = __shfl(sidx, e + 3);
            const float w0 = __shfl(wv, e),       w1 = __shfl(wv, e + 1);
            const float w2 = __shfl(wv, e + 2),   w3 = __shfl(wv, e + 3);
            const float4 x0 = ((const float4*)(h + (long)i0 * DD))[lane];
            const float4 x1 = ((const float4*)(h + (long)i1 * DD))[lane];
            const float4 x2 = ((const float4*)(h + (long)i2 * DD))[lane];
            const float4 x3 = ((const float4*)(h + (long)i3 * DD))[lane];
            acc.x += w0 * x0.x + w1 * x1.x + w2 * x2.x + w3 * x3.x;
            acc.y += w0 * x0.y + w1 * x1.y + w2 * x2.y + w3 * x3.y;
            acc.z += w0 * x0.z + w1 * x1.z + w2 * x2.z + w3 * x3.z;
            acc.w += w0 * x0.w + w1 * x1.w + w2 * x2.w + w3 * x3.w;
        }
        for (; e < nb; ++e) {
            const int   s = __shfl(sidx, e);
            const float w = __shfl(wv, e);
            const float4 x = ((const float4*)(h + (long)s * DD))[lane];
            acc.x += w * x.x; acc.y += w * x.y; acc.z += w * x.z; acc.w += w * x.w;
        }
    }
    const float4 bv = ((const float4*)bias)[lane];
    acc.x += bv.x; acc.y += bv.y; acc.z += bv.z; acc.w += bv.w;

    if (outF) {
        ((float4*)(outF + (long)node * DD))[lane] = acc;
    } else {
        u16* op = outBF + (long)node * DD + lane * 4;
        op[0] = f2bf(acc.x); op[1] = f2bf(acc.y);
        op[2] = f2bf(acc.z); op[3] = f2bf(acc.w);
    }
}

// ---------------------------------------------------------------------------
extern "C" void kernel_launch(void* const* d_in, const int* in_sizes, int n_in,
                              void* d_out, int out_size, void* d_ws, size_t ws_size,
                              hipStream_t stream)
{
    (void)n_in; (void)out_size; (void)ws_size;
    const float* emb0  = (const float*)d_in[0];
    const float* A     = (const float*)d_in[1];
    const int*   eiS   = (const int*)d_in[2];
    const int*   eiU   = (const int*)d_in[3];
    const float* Wsame = (const float*)d_in[4];
    const float* bsame = (const float*)d_in[5];
    const float* Wtop  = (const float*)d_in[6];
    const float* btop  = (const float*)d_in[7];
    const int E = in_sizes[2] / 2;

    char* ws = (char*)d_ws;
    u16*   embT   = (u16*)  (ws + 0);           // 4 MiB   [256][8192] bf16
    float* Cacc   = (float*)(ws + 4194304);     // 64 MiB  KS slabs [8192][256] f32
    float* emb1   = (float*)(ws + 71303168);    // 8 MiB   [8192][256] f32
    u16*   xbf    = (u16*)  (ws + 79691776);    // 4 MiB   [8192][256] bf16
    u16*   WT     = (u16*)  (ws + 83886080);    // 256 KiB 2x [256][256] bf16
    float* rsb    = (float*)(ws + 84148224);    // 256 KiB KS slabs [8192] f32
    float* dinv2  = (float*)(ws + 84410368);    // 64 KiB  2x [8192]
    int*   counts = (int*)  (ws + 84475904);    // 64 KiB  2x [8192]
    int*   offs2  = (int*)  (ws + 84541440);    // 2x (NN+1) ints
    int*   cursor = (int*)  (ws + 84607232);    // 64 KiB  2x [8192]
    int*   csums  = (int*)  (ws + 84672768);    // 512 B   64 ints
    int*   csr2   = (int*)  (ws + 84673280);    // 2x CSRSZ ints (~4.3 MiB)

    const dim3 blk(256);
    const dim3 gDense(128, 1, KS), gGcn(128, 1, 1);
    const dim3 gG(NN / 4);

    // fused transposes (emb + both weights), then one cooperative CSR build
    trans_k<<<dim3(544), blk, 0, stream>>>(emb0, Wsame, Wtop, embT, WT);
    {
        const int* a0 = eiS; const int* a1 = eiU; int a2 = E;
        int* a3 = counts; int* a4 = offs2; int* a5 = cursor;
        float* a6 = dinv2; int* a7 = csr2; int* a8 = csums;
        void* args[] = { &a0, &a1, &a2, &a3, &a4, &a5, &a6, &a7, &a8 };
        hipLaunchCooperativeKernel((const void*)csr_k, dim3(1024), blk, args, 0, stream);
    }

    // ---- level 0 (slab split-K: no memset, no atomics)
    gemm_k<true, true><<<gDense, blk, 0, stream>>>(A, NN, embT, NN, Cacc, rsb, NN / KS);
    norm0_k<<<dim3(128, 4), blk, 0, stream>>>(Cacc, rsb, emb0, emb1, embT);

    // ---- level 1
    gemm_k<true, true><<<gDense, blk, 0, stream>>>(A + (size_t)NN * NN, NN, embT, NN, Cacc, rsb, NN / KS);
    norm1_k<<<dim3(2048), blk, 0, stream>>>(Cacc, rsb, emb1, xbf);

    // ---- GCN layer 1 (same_level)
    gemm_k<false, false><<<gGcn, blk, 0, stream>>>(xbf, DD, WT, DD, Cacc, nullptr, 256);
    gather_k<<<gG, blk, 0, stream>>>(Cacc, offs2, csr2, dinv2, bsame, xbf, nullptr);

    // ---- GCN layer 2 (up2down)
    gemm_k<false, false><<<gGcn, blk, 0, stream>>>(xbf, DD, WT + DD * DD, DD, Cacc, nullptr, 256);
    gather_k<<<gG, blk, 0, stream>>>(Cacc, offs2 + (NN + 1), csr2 + CSRSZ,
                                     dinv2 + NN, btop, nullptr, (float*)d_out);
}